// Round 7
// baseline (18388.887 us; speedup 1.0000x reference)
//
#include <hip/hip_runtime.h>
#include <stdint.h>
#include <stddef.h>

// Problem constants: B=32, T=512, FD=256, NH=1024, NC=512, NOUT=8
// M = B*T = 16384 rows everywhere.
// Established: device inputs f32; output f32; R4-R6 passed (absmax 3.9e-3).
// R7: scan restructure — 8 WGs x 512 thr per direction (was 32x256):
//     8-wide barrier, 8-lane poll w/ s_sleep(2), 2 A-tiles per wave.

typedef short  short8  __attribute__((ext_vector_type(8)));
typedef short  short4v __attribute__((ext_vector_type(4)));
typedef float  float4v __attribute__((ext_vector_type(4)));
typedef unsigned long long u64;

__device__ inline float b2f(short x){
  union { unsigned u; float f; } v; v.u = ((unsigned)(unsigned short)x) << 16; return v.f;
}
__device__ inline short f2b(float f){
  union { float f; unsigned u; } v; v.f = f;
  unsigned r = (v.u + 0x7fffu + ((v.u >> 16) & 1u)) >> 16;
  return (short)r;
}
__device__ inline float sigm(float x){ return 1.f / (1.f + __expf(-x)); }
__device__ inline float tanh_(float x){ return 2.f / (1.f + __expf(-2.f*x)) - 1.f; }

// ---------------------------------------------------------------------------
// Input dtype detection: true-bf16 normals never have exponent >= 0xC0;
// f32 low half-words are uniform -> ~25% exceed.
// ---------------------------------------------------------------------------
__global__ __launch_bounds__(256) void detect_f32(
    const unsigned short* __restrict__ p, unsigned* __restrict__ flag)
{
  const int tid = threadIdx.x;
  unsigned h = 0;
  for (int i = tid; i < 1024; i += 256){
    const unsigned e = (p[i] >> 7) & 0xFFu;
    if (e >= 0xC0u) ++h;
  }
#pragma unroll
  for (int off=32; off>0; off>>=1) h += __shfl_xor(h, off, 64);
  __shared__ unsigned sh[4];
  if ((tid&63)==0) sh[tid>>6] = h;
  __syncthreads();
  if (tid==0) *flag = (sh[0]+sh[1]+sh[2]+sh[3] >= 8u) ? 1u : 0u;
}

// Normalize a float tensor to bf16 (identity copy if already bf16).
__global__ __launch_bounds__(256) void to_bf16(
    const void* __restrict__ src, short* __restrict__ dst, int n,
    const unsigned* __restrict__ flag)
{
  const int i = blockIdx.x*256 + threadIdx.x;
  if (i >= n) return;
  if (*flag) dst[i] = f2b(((const float*)src)[i]);
  else       dst[i] = ((const short*)src)[i];
}

// ---------------------------------------------------------------------------
// GEMM: C[M,N] = bf16( A[M,K] @ W[N,K]^T + bias1[n] (+ bias2[n]) ).
// 128x128 block tile, BK=32, 4 waves, 16x16x32 bf16 MFMA. All dims multiples.
// ---------------------------------------------------------------------------
__global__ __launch_bounds__(256) void gemm_bt(
    const short* __restrict__ A, const short* __restrict__ W,
    short* __restrict__ C, const short* __restrict__ bias1,
    const short* __restrict__ bias2, int N, int K)
{
  __shared__ __align__(16) short lA[128*40];
  __shared__ __align__(16) short lW[128*40];
  const int tid  = threadIdx.x;
  const int lane = tid & 63, wv = tid >> 6;
  const int wm = wv >> 1, wn = wv & 1;
  const int quad = lane >> 4, l15 = lane & 15;
  const long m0 = (long)blockIdx.y * 128, n0 = (long)blockIdx.x * 128;

  float4v acc[4][4];
#pragma unroll
  for (int i=0;i<4;++i)
#pragma unroll
    for (int j=0;j<4;++j) acc[i][j] = (float4v)0.f;

  const int r  = tid >> 2;
  const int kc = tid & 3;
  const int nkt = K >> 5;
  for (int kt = 0; kt < nkt; ++kt) {
    __syncthreads();
    const short* ga = A + (m0 + r) * (long)K + kt*32 + kc*8;
    const short* gw = W + (n0 + r) * (long)K + kt*32 + kc*8;
    short8 a0 = *(const short8*)ga;
    short8 a1 = *(const short8*)(ga + 64*(long)K);
    short8 w0 = *(const short8*)gw;
    short8 w1 = *(const short8*)(gw + 64*(long)K);
    *(short8*)&lA[r*40 + kc*8]        = a0;
    *(short8*)&lA[(r+64)*40 + kc*8]   = a1;
    *(short8*)&lW[r*40 + kc*8]        = w0;
    *(short8*)&lW[(r+64)*40 + kc*8]   = w1;
    __syncthreads();
    short8 af[4], bfr[4];
#pragma unroll
    for (int i=0;i<4;++i) af[i]  = *(const short8*)&lA[(wm*64 + i*16 + l15)*40 + quad*8];
#pragma unroll
    for (int j=0;j<4;++j) bfr[j] = *(const short8*)&lW[(wn*64 + j*16 + l15)*40 + quad*8];
#pragma unroll
    for (int i=0;i<4;++i)
#pragma unroll
      for (int j=0;j<4;++j)
        acc[i][j] = __builtin_amdgcn_mfma_f32_16x16x32_bf16(af[i], bfr[j], acc[i][j], 0, 0, 0);
  }
#pragma unroll
  for (int j=0;j<4;++j){
    const long n = n0 + wn*64 + j*16 + l15;
    float bs = b2f(bias1[n]);
    if (bias2) bs += b2f(bias2[n]);
#pragma unroll
    for (int i=0;i<4;++i){
      const long mb = m0 + wm*64 + i*16 + quad*4;
#pragma unroll
      for (int g=0; g<4; ++g)
        C[(mb+g)*(long)N + n] = f2b(acc[i][j][g] + bs);
    }
  }
}

// ---------------------------------------------------------------------------
// Row-wise LayerNorm (eps=1e-5) + LeakyReLU(0.01) (+ optional pad-mask zero).
// ---------------------------------------------------------------------------
__global__ __launch_bounds__(256) void ln_lrelu(
    const short* __restrict__ X, const short* __restrict__ g,
    const short* __restrict__ be, short* __restrict__ out,
    const int* __restrict__ lens, const int domask)
{
  const int row = blockIdx.x, tid = threadIdx.x;
  const short* xr = X + (size_t)row * 1024;
  short4v xv = *(const short4v*)(xr + tid*4);
  float v[4];
#pragma unroll
  for (int k=0;k<4;++k) v[k] = b2f(xv[k]);
  float s  = v[0]+v[1]+v[2]+v[3];
  float sq = v[0]*v[0]+v[1]*v[1]+v[2]*v[2]+v[3]*v[3];
#pragma unroll
  for (int off=32; off>0; off>>=1){
    s  += __shfl_xor(s,  off, 64);
    sq += __shfl_xor(sq, off, 64);
  }
  __shared__ float red[8];
  if ((tid&63)==0){ red[tid>>6] = s; red[4+(tid>>6)] = sq; }
  __syncthreads();
  s  = red[0]+red[1]+red[2]+red[3];
  sq = red[4]+red[5]+red[6]+red[7];
  const float mean = s * (1.f/1024.f);
  const float var  = sq * (1.f/1024.f) - mean*mean;
  const float rstd = rsqrtf(var + 1e-5f);
  float zmul = 1.f;
  if (domask){ const int b = row >> 9, t = row & 511; if (t >= lens[b]) zmul = 0.f; }
  short4v o;
#pragma unroll
  for (int k=0;k<4;++k){
    const int n = tid*4 + k;
    float y = (v[k]-mean)*rstd*b2f(g[n]) + b2f(be[n]);
    y = (y >= 0.f) ? y : 0.01f*y;
    o[k] = f2b(y * zmul);
  }
  *(short4v*)(out + (size_t)row*1024 + tid*4) = o;
}

// ---------------------------------------------------------------------------
// Persistent bidirectional LSTM scan — 8 WGs x 512 thr per direction.
// WG owns 64 units; wave w: gate g=w>>1 (torch i,f,g,o), unit-half hh=w&1,
// 2 A-tiles of 16 rows (128 weight VGPRs/thread). h state [dir][buf][32][256]
// dwords (packed 2xbf16), coherent agent-scope atomics only (L3, no L2).
// Barrier: 8 slots/dir, 64B apart; arrival = relaxed store after waitcnt
// drain; poll = lanes 0..7 of wave 0 only, s_sleep(2) backoff.
// ---------------------------------------------------------------------------
__global__ __launch_bounds__(512) void lstm_scan(
    const short* __restrict__ xp, const int xp_cols, const int dir0,
    const short* __restrict__ whh,      // layer base: [2][2048][512]
    unsigned* __restrict__ hstate32,    // [2][2][32][256] dwords
    short* __restrict__ hout,           // [32][512][1024]
    unsigned* __restrict__ slots)       // per local dir: 8 slots, 16 uints apart
{
  const int wg = blockIdx.x;
  const int dloc = wg >> 3, d = dir0 + dloc, wgd = wg & 7;
  const int u0g = wgd * 64;                    // global unit base of this WG
  const int tid = threadIdx.x, lane = tid & 63, wv = tid >> 6;
  const int g = wv >> 1, hh = wv & 1;
  const int quad = lane >> 4, l15 = lane & 15;
  unsigned* myslots = slots + dloc*512;

  // A fragments: 2 tiles x 16 ks (rows = gate g, units u0g+32hh+16i+l15)
  short8 af[2][16];
#pragma unroll
  for (int i=0;i<2;++i){
    const short* wr = whh + ((size_t)d*2048 + g*512 + u0g + 32*hh + 16*i + l15)*512 + quad*8;
#pragma unroll
    for (int ks=0; ks<16; ++ks) af[i][ks] = *(const short8*)(wr + ks*32);
  }

  // gate-math ownership: thread -> (batch bb, 4 units u0g+4j..+3)
  const int bb = tid >> 4, j = tid & 15;
  u64* hq0 = (u64*)hstate32;
  __hip_atomic_store(hq0 + (size_t)(d*2)*32*128 + (size_t)bb*128 + u0g/4 + j, (u64)0,
                     __ATOMIC_RELAXED, __HIP_MEMORY_SCOPE_AGENT);
  __builtin_amdgcn_s_waitcnt(0);
  __syncthreads();
  if (tid==0)
    __hip_atomic_store(myslots + wgd*16, 1u, __ATOMIC_RELAXED, __HIP_MEMORY_SCOPE_AGENT);

  float cst[4] = {0.f,0.f,0.f,0.f};
  __shared__ float gl[4][64][33];

  for (int step=0; step<512; ++step){
    const int t = d ? (511-step) : step;
    // xp prefetch (barrier-independent, overlaps the spin)
    short4v x[2][2];
#pragma unroll
    for (int i=0;i<2;++i)
#pragma unroll
      for (int half=0; half<2; ++half){
        const size_t gb = (size_t)(d-dir0)*2048 + g*512 + u0g + 32*hh + 16*i + quad*4;
        x[i][half] = *(const short4v*)(xp + ((size_t)(half*16 + l15)*512 + t)*xp_cols + gb);
      }
    // wait for all 8 WGs of this direction (lanes 0..7 poll, others trivially pass)
    if (tid < 64){
      const unsigned tgt = (unsigned)(step+1);
      unsigned v = 0xFFFFFFFFu;
      while (true){
        if (lane < 8)
          v = __hip_atomic_load(myslots + lane*16, __ATOMIC_RELAXED, __HIP_MEMORY_SCOPE_AGENT);
        if (__all((int)(v >= tgt))) break;
        __builtin_amdgcn_s_sleep(2);
      }
    }
    __syncthreads();

    float4v acc[2][2];
#pragma unroll
    for (int i=0;i<2;++i)
#pragma unroll
      for (int half=0; half<2; ++half)
#pragma unroll
        for (int r=0;r<4;++r) acc[i][half][r] = b2f(x[i][half][r]);

    // h reads: coherent u64 loads from L3; one B-frag feeds both A-tiles
    const u64* hq = (const u64*)(hstate32 + (size_t)(d*2 + (step&1))*32*256);
#pragma unroll
    for (int half=0; half<2; ++half){
      const size_t rb = (size_t)(half*16 + l15)*128 + quad*2;
#pragma unroll
      for (int kb=0; kb<4; ++kb){
        u64 q[4][2];
#pragma unroll
        for (int k2=0;k2<4;++k2){
          const size_t bi = rb + (size_t)(kb*4+k2)*8;
          q[k2][0] = __hip_atomic_load(hq + bi,     __ATOMIC_RELAXED, __HIP_MEMORY_SCOPE_AGENT);
          q[k2][1] = __hip_atomic_load(hq + bi + 1, __ATOMIC_RELAXED, __HIP_MEMORY_SCOPE_AGENT);
        }
#pragma unroll
        for (int k2=0;k2<4;++k2){
          const int ks = kb*4 + k2;
          union { u64 q[2]; short8 s; } c;
          c.q[0]=q[k2][0]; c.q[1]=q[k2][1];
          acc[0][half] = __builtin_amdgcn_mfma_f32_16x16x32_bf16(af[0][ks], c.s, acc[0][half], 0, 0, 0);
          acc[1][half] = __builtin_amdgcn_mfma_f32_16x16x32_bf16(af[1][ks], c.s, acc[1][half], 0, 0, 0);
        }
      }
    }
#pragma unroll
    for (int i=0;i<2;++i)
#pragma unroll
      for (int half=0; half<2; ++half)
#pragma unroll
        for (int r=0;r<4;++r)
          gl[g][32*hh + 16*i + quad*4 + r][half*16 + l15] = acc[i][half][r];
    __syncthreads();

    // gate math: 4 units per thread
    float hv[4];
#pragma unroll
    for (int i=0;i<4;++i){
      const int uloc = 4*j + i;
      const float gi = gl[0][uloc][bb], gf = gl[1][uloc][bb];
      const float gg = gl[2][uloc][bb], go = gl[3][uloc][bb];
      const float c = sigm(gf)*cst[i] + sigm(gi)*tanh_(gg);
      cst[i] = c;
      hv[i] = sigm(go) * tanh_(c);
    }
    const unsigned w0 = (unsigned)(unsigned short)f2b(hv[0])
                      | ((unsigned)(unsigned short)f2b(hv[1]) << 16);
    const unsigned w1 = (unsigned)(unsigned short)f2b(hv[2])
                      | ((unsigned)(unsigned short)f2b(hv[3]) << 16);
    const u64 hw = (u64)w0 | ((u64)w1 << 32);
    u64* hn = (u64*)(hstate32 + (size_t)(d*2 + ((step+1)&1))*32*256);
    __hip_atomic_store(hn + (size_t)bb*128 + u0g/4 + j, hw,
                       __ATOMIC_RELAXED, __HIP_MEMORY_SCOPE_AGENT);
    *(u64*)&hout[((size_t)bb*512 + t)*1024 + d*512 + u0g + 4*j] = hw;
    __builtin_amdgcn_s_waitcnt(0);   // drain coherent stores to L3
    __syncthreads();
    if (tid==0)
      __hip_atomic_store(myslots + wgd*16, (unsigned)(step+2),
                         __ATOMIC_RELAXED, __HIP_MEMORY_SCOPE_AGENT);
  }
}

// ---------------------------------------------------------------------------
// Attention (window_len=1) + classifier. One block per batch element.
// b_u omitted: constant shift cancels in softmax. Output: f32.
// ---------------------------------------------------------------------------
__global__ __launch_bounds__(256) void attn_cls(
    const short* __restrict__ hseq, const short* __restrict__ wu,
    const short* __restrict__ Wc, const short* __restrict__ bc,
    const int* __restrict__ lens, float* __restrict__ out)
{
  const int b = blockIdx.x, tid = threadIdx.x, lane = tid & 63, wv = tid >> 6;
  const int len = lens[b];
  __shared__ float wus[1024];
  __shared__ float sc[512];
  __shared__ float redx[8];
  __shared__ float pooled[1024];
  for (int i=tid; i<1024; i+=256) wus[i] = b2f(wu[i]);
  __syncthreads();
  const short* hb = hseq + (size_t)b*512*1024;
  for (int t=wv; t<512; t+=4){
    const short* hr = hb + (size_t)t*1024;
    float s = 0.f;
#pragma unroll
    for (int j=0;j<16;++j) s += b2f(hr[lane + j*64]) * wus[lane + j*64];
#pragma unroll
    for (int off=32; off>0; off>>=1) s += __shfl_xor(s, off, 64);
    if (lane==0) sc[t] = (t < len) ? s : -3.0e38f;
  }
  __syncthreads();
  float m = -3.0e38f;
  for (int i=tid;i<512;i+=256) m = fmaxf(m, sc[i]);
#pragma unroll
  for (int off=32; off>0; off>>=1) m = fmaxf(m, __shfl_xor(m, off, 64));
  if (lane==0) redx[wv] = m;
  __syncthreads();
  m = fmaxf(fmaxf(redx[0],redx[1]), fmaxf(redx[2],redx[3]));
  float ssum = 0.f;
  for (int i=tid;i<512;i+=256){
    float e = (i<len) ? __expf(sc[i]-m) : 0.f;
    sc[i] = e;
    ssum += e;
  }
#pragma unroll
  for (int off=32; off>0; off>>=1) ssum += __shfl_xor(ssum, off, 64);
  if (lane==0) redx[4+wv] = ssum;
  __syncthreads();
  ssum = redx[4]+redx[5]+redx[6]+redx[7];
  const float inv = 1.f/ssum;
  float4v pa = (float4v)0.f;
  const int k0 = tid*4;
  for (int t=0; t<len; ++t){
    const float a = sc[t];
    short4v hv = *(const short4v*)(hb + (size_t)t*1024 + k0);
    pa[0] += a*b2f(hv[0]); pa[1] += a*b2f(hv[1]);
    pa[2] += a*b2f(hv[2]); pa[3] += a*b2f(hv[3]);
  }
  pooled[k0+0] = pa[0]*inv; pooled[k0+1] = pa[1]*inv;
  pooled[k0+2] = pa[2]*inv; pooled[k0+3] = pa[3]*inv;
  __syncthreads();
  const int j = tid >> 5, l32 = tid & 31;
  float s2 = 0.f;
  for (int kk=l32; kk<1024; kk+=32) s2 += b2f(Wc[j*1024+kk]) * pooled[kk];
#pragma unroll
  for (int off=16; off>0; off>>=1) s2 += __shfl_xor(s2, off, 32);
  if (l32==0) out[b*8+j] = s2 + b2f(bc[j]);
}

// ---------------------------------------------------------------------------
extern "C" void kernel_launch(void* const* d_in, const int* in_sizes, int n_in,
                              void* d_out, int out_size, void* d_ws, size_t ws_size,
                              hipStream_t stream)
{
  (void)in_sizes; (void)n_in; (void)out_size;
  const int*   lens = (const int*)d_in[1];
  float* outp = (float*)d_out;

  const size_t SZ_XP_A = (size_t)16384*4096*2;   // 134,217,728 B
  const size_t SZ_XP_B = (size_t)16384*2048*2;   //  67,108,864 B
  const size_t SZ_H    = (size_t)16384*1024*2;   //  33,554,432 B
  const size_t SZ_HS   = 262144;                 // 2 dirs x 2 bufs x 32 x 256 dwords
  const size_t SZ_CNT  = 16384;
  const size_t SZ_NORM = 37000000;               // bf16 copies of all inputs
  const bool planA = ws_size >= SZ_XP_A + 2*SZ_H + SZ_HS + SZ_CNT + SZ_NORM;
  const bool planB = !planA && ws_size >= SZ_XP_B + 2*SZ_H + SZ_HS + SZ_CNT + SZ_NORM;
  if (!planA && !planB) return;  // clean failure beats a core dump
  const size_t xpsz = planA ? SZ_XP_A : SZ_XP_B;

  char* ws = (char*)d_ws;
  short*    XP  = (short*)ws;
  short*    HB  = (short*)(ws + xpsz);
  short*    HC  = (short*)(ws + xpsz + SZ_H);
  unsigned* HS32= (unsigned*)(ws + xpsz + 2*SZ_H);
  unsigned* CNT = (unsigned*)(ws + xpsz + 2*SZ_H + SZ_HS);
  unsigned* FLAG = CNT + 4000;
  short*    pool = (short*)(ws + xpsz + 2*SZ_H + SZ_HS + SZ_CNT);

  // carve bf16 copies (128-element aligned)
  size_t off = 0;
  auto carve = [&](size_t n){ short* p = pool + off; off += (n + 127) & ~(size_t)127; return p; };
  short* x   = carve(4194304);
  short* W1  = carve(262144);
  short* b1  = carve(1024);
  short* g1  = carve(1024);
  short* be1 = carve(1024);
  short* W2  = carve(1048576);
  short* b2  = carve(1024);
  short* g2  = carve(1024);
  short* be2 = carve(1024);
  short* wih = carve(8388608);
  short* whh = carve(4194304);
  short* bih = carve(8192);
  short* bhh = carve(8192);
  short* wu  = carve(1024);
  short* Wc  = carve(8192);
  short* bc  = carve(8);

  hipMemsetAsync(CNT, 0, SZ_CNT, stream);
  detect_f32<<<1, 256, 0, stream>>>((const unsigned short*)d_in[0], FLAG);

  struct { int idx; short* dst; int n; } cv[16] = {
    {0,x,4194304},{2,W1,262144},{3,b1,1024},{4,g1,1024},{5,be1,1024},
    {6,W2,1048576},{7,b2,1024},{8,g2,1024},{9,be2,1024},
    {10,wih,8388608},{11,whh,4194304},{12,bih,8192},{13,bhh,8192},
    {14,wu,1024},{16,Wc,8192},{17,bc,8}
  };
  for (int i=0;i<16;++i)
    to_bf16<<<(cv[i].n + 255)/256, 256, 0, stream>>>(d_in[cv[i].idx], cv[i].dst, cv[i].n, FLAG);

  dim3 blk(256);
  // extract MLP
  gemm_bt<<<dim3(8,128),  blk, 0, stream>>>(x,  W1, XP, b1, nullptr, 1024, 256);
  ln_lrelu<<<16384, blk, 0, stream>>>(XP, g1, be1, HB, lens, 0);
  gemm_bt<<<dim3(8,128),  blk, 0, stream>>>(HB, W2, XP, b2, nullptr, 1024, 1024);
  ln_lrelu<<<16384, blk, 0, stream>>>(XP, g2, be2, HC, lens, 1);   // + pad mask

  const short* lin[2]  = { HC, HB };   // layer inputs
  short*       lout[2] = { HB, HC };   // layer outputs
  for (int l = 0; l < 2; ++l){
    const short* whh_l = whh + (size_t)l*2*2048*512;
    if (planA){
      gemm_bt<<<dim3(32,128), blk, 0, stream>>>(
          lin[l], wih + (size_t)l*4096*1024, XP,
          bih + l*4096, bhh + l*4096, 4096, 1024);
      lstm_scan<<<16, 512, 0, stream>>>(XP, 4096, 0, whh_l, HS32, lout[l], CNT + l*1024);
    } else {
      for (int d = 0; d < 2; ++d){
        gemm_bt<<<dim3(16,128), blk, 0, stream>>>(
            lin[l], wih + ((size_t)(l*2+d))*2048*1024, XP,
            bih + (l*2+d)*2048, bhh + (l*2+d)*2048, 2048, 1024);
        lstm_scan<<<8, 512, 0, stream>>>(XP, 2048, d, whh_l, HS32, lout[l],
                                         CNT + (l*2+d)*512);
      }
    }
  }
  // attention + classifier
  attn_cls<<<32, blk, 0, stream>>>(HC, wu, Wc, bc, lens, outp);
}

// Round 8
// 5646.724 us; speedup vs baseline: 3.2566x; 3.2566x over previous
//
#include <hip/hip_runtime.h>
#include <stdint.h>
#include <stddef.h>

// Problem constants: B=32, T=512, FD=256, NH=1024, NC=512, NOUT=8
// Established: device inputs f32; output f32; R4-R7 passed (absmax 3.9e-3).
// R8: R6 structure (32 WG x 256 thr per dir) + cooperative LDS h-staging:
//     one full-MLP coherent load round trip per step (was 4-8 serialized),
//     MFMA B-frags from LDS (ds_read_b128), 4x less global h traffic.

typedef short  short8  __attribute__((ext_vector_type(8)));
typedef short  short4v __attribute__((ext_vector_type(4)));
typedef float  float4v __attribute__((ext_vector_type(4)));
typedef unsigned long long u64;

__device__ inline float b2f(short x){
  union { unsigned u; float f; } v; v.u = ((unsigned)(unsigned short)x) << 16; return v.f;
}
__device__ inline short f2b(float f){
  union { float f; unsigned u; } v; v.f = f;
  unsigned r = (v.u + 0x7fffu + ((v.u >> 16) & 1u)) >> 16;
  return (short)r;
}
__device__ inline float sigm(float x){ return 1.f / (1.f + __expf(-x)); }
__device__ inline float tanh_(float x){ return 2.f / (1.f + __expf(-2.f*x)) - 1.f; }

// ---------------------------------------------------------------------------
// Input dtype detection: true-bf16 normals never have exponent >= 0xC0;
// f32 low half-words are uniform -> ~25% exceed.
// ---------------------------------------------------------------------------
__global__ __launch_bounds__(256) void detect_f32(
    const unsigned short* __restrict__ p, unsigned* __restrict__ flag)
{
  const int tid = threadIdx.x;
  unsigned h = 0;
  for (int i = tid; i < 1024; i += 256){
    const unsigned e = (p[i] >> 7) & 0xFFu;
    if (e >= 0xC0u) ++h;
  }
#pragma unroll
  for (int off=32; off>0; off>>=1) h += __shfl_xor(h, off, 64);
  __shared__ unsigned sh[4];
  if ((tid&63)==0) sh[tid>>6] = h;
  __syncthreads();
  if (tid==0) *flag = (sh[0]+sh[1]+sh[2]+sh[3] >= 8u) ? 1u : 0u;
}

// Normalize a float tensor to bf16 (identity copy if already bf16).
__global__ __launch_bounds__(256) void to_bf16(
    const void* __restrict__ src, short* __restrict__ dst, int n,
    const unsigned* __restrict__ flag)
{
  const int i = blockIdx.x*256 + threadIdx.x;
  if (i >= n) return;
  if (*flag) dst[i] = f2b(((const float*)src)[i]);
  else       dst[i] = ((const short*)src)[i];
}

// ---------------------------------------------------------------------------
// GEMM: C[M,N] = bf16( A[M,K] @ W[N,K]^T + bias1[n] (+ bias2[n]) ).
// 128x128 block tile, BK=32, 4 waves, 16x16x32 bf16 MFMA. All dims multiples.
// ---------------------------------------------------------------------------
__global__ __launch_bounds__(256) void gemm_bt(
    const short* __restrict__ A, const short* __restrict__ W,
    short* __restrict__ C, const short* __restrict__ bias1,
    const short* __restrict__ bias2, int N, int K)
{
  __shared__ __align__(16) short lA[128*40];
  __shared__ __align__(16) short lW[128*40];
  const int tid  = threadIdx.x;
  const int lane = tid & 63, wv = tid >> 6;
  const int wm = wv >> 1, wn = wv & 1;
  const int quad = lane >> 4, l15 = lane & 15;
  const long m0 = (long)blockIdx.y * 128, n0 = (long)blockIdx.x * 128;

  float4v acc[4][4];
#pragma unroll
  for (int i=0;i<4;++i)
#pragma unroll
    for (int j=0;j<4;++j) acc[i][j] = (float4v)0.f;

  const int r  = tid >> 2;
  const int kc = tid & 3;
  const int nkt = K >> 5;
  for (int kt = 0; kt < nkt; ++kt) {
    __syncthreads();
    const short* ga = A + (m0 + r) * (long)K + kt*32 + kc*8;
    const short* gw = W + (n0 + r) * (long)K + kt*32 + kc*8;
    short8 a0 = *(const short8*)ga;
    short8 a1 = *(const short8*)(ga + 64*(long)K);
    short8 w0 = *(const short8*)gw;
    short8 w1 = *(const short8*)(gw + 64*(long)K);
    *(short8*)&lA[r*40 + kc*8]        = a0;
    *(short8*)&lA[(r+64)*40 + kc*8]   = a1;
    *(short8*)&lW[r*40 + kc*8]        = w0;
    *(short8*)&lW[(r+64)*40 + kc*8]   = w1;
    __syncthreads();
    short8 af[4], bfr[4];
#pragma unroll
    for (int i=0;i<4;++i) af[i]  = *(const short8*)&lA[(wm*64 + i*16 + l15)*40 + quad*8];
#pragma unroll
    for (int j=0;j<4;++j) bfr[j] = *(const short8*)&lW[(wn*64 + j*16 + l15)*40 + quad*8];
#pragma unroll
    for (int i=0;i<4;++i)
#pragma unroll
      for (int j=0;j<4;++j)
        acc[i][j] = __builtin_amdgcn_mfma_f32_16x16x32_bf16(af[i], bfr[j], acc[i][j], 0, 0, 0);
  }
#pragma unroll
  for (int j=0;j<4;++j){
    const long n = n0 + wn*64 + j*16 + l15;
    float bs = b2f(bias1[n]);
    if (bias2) bs += b2f(bias2[n]);
#pragma unroll
    for (int i=0;i<4;++i){
      const long mb = m0 + wm*64 + i*16 + quad*4;
#pragma unroll
      for (int g=0; g<4; ++g)
        C[(mb+g)*(long)N + n] = f2b(acc[i][j][g] + bs);
    }
  }
}

// ---------------------------------------------------------------------------
// Row-wise LayerNorm (eps=1e-5) + LeakyReLU(0.01) (+ optional pad-mask zero).
// ---------------------------------------------------------------------------
__global__ __launch_bounds__(256) void ln_lrelu(
    const short* __restrict__ X, const short* __restrict__ g,
    const short* __restrict__ be, short* __restrict__ out,
    const int* __restrict__ lens, const int domask)
{
  const int row = blockIdx.x, tid = threadIdx.x;
  const short* xr = X + (size_t)row * 1024;
  short4v xv = *(const short4v*)(xr + tid*4);
  float v[4];
#pragma unroll
  for (int k=0;k<4;++k) v[k] = b2f(xv[k]);
  float s  = v[0]+v[1]+v[2]+v[3];
  float sq = v[0]*v[0]+v[1]*v[1]+v[2]*v[2]+v[3]*v[3];
#pragma unroll
  for (int off=32; off>0; off>>=1){
    s  += __shfl_xor(s,  off, 64);
    sq += __shfl_xor(sq, off, 64);
  }
  __shared__ float red[8];
  if ((tid&63)==0){ red[tid>>6] = s; red[4+(tid>>6)] = sq; }
  __syncthreads();
  s  = red[0]+red[1]+red[2]+red[3];
  sq = red[4]+red[5]+red[6]+red[7];
  const float mean = s * (1.f/1024.f);
  const float var  = sq * (1.f/1024.f) - mean*mean;
  const float rstd = rsqrtf(var + 1e-5f);
  float zmul = 1.f;
  if (domask){ const int b = row >> 9, t = row & 511; if (t >= lens[b]) zmul = 0.f; }
  short4v o;
#pragma unroll
  for (int k=0;k<4;++k){
    const int n = tid*4 + k;
    float y = (v[k]-mean)*rstd*b2f(g[n]) + b2f(be[n]);
    y = (y >= 0.f) ? y : 0.01f*y;
    o[k] = f2b(y * zmul);
  }
  *(short4v*)(out + (size_t)row*1024 + tid*4) = o;
}

// ---------------------------------------------------------------------------
// Persistent bidirectional LSTM scan — R6 structure + LDS h-staging.
// Grid = 32*ndir WGs x 256 thr. WG dir = dir0 + (blk>>5); 16 units per WG.
// Wave w computes gate w (torch i,f,g,o); whh A-frags in VGPRs.
// h state global [dir][buf][32][256] dwords (packed 2xbf16), coherent
// agent-scope atomics only. Per step: ONE cooperative stage (each thread 16
// independent u64 coherent loads = full 32KB, single latency round trip) ->
// LDS (row stride 260 dwords) -> ds_read b128 B-frags for MFMA.
// Release = waitcnt drain + syncthreads + relaxed flag store (8th round w/
// this protocol, bit-identical results R4-R7).
// ---------------------------------------------------------------------------
__global__ __launch_bounds__(256) void lstm_scan(
    const short* __restrict__ xp, const int xp_cols, const int dir0,
    const short* __restrict__ whh,      // layer base: [2][2048][512]
    unsigned* __restrict__ hstate32,    // [2][2][32][256] dwords
    short* __restrict__ hout,           // [32][512][1024]
    unsigned* __restrict__ slots)       // per local dir: 32 slots, 64B apart
{
  const int wg = blockIdx.x;
  const int dloc = wg >> 5, d = dir0 + dloc, wgd = wg & 31;
  const int u0 = wgd * 16;
  const int tid = threadIdx.x, lane = tid & 63, wv = tid >> 6;
  const int quad = lane >> 4, l15 = lane & 15;
  unsigned* myslots = slots + dloc*512;
  unsigned* pollp   = myslots + (lane & 31)*16;

  short8 af[16];
  {
    const short* wr = whh + ((size_t)d*2048 + wv*512 + u0 + l15)*512 + quad*8;
#pragma unroll
    for (int ks=0; ks<16; ++ks) af[ks] = *(const short8*)(wr + ks*32);
  }

  // h-state init + gate-math ownership: thread = (batch bb, unit-pair pp)
  const int bb = tid >> 3, pp = tid & 7;
  __hip_atomic_store(hstate32 + (size_t)(d*2)*32*256 + (size_t)bb*256 + u0/2 + pp, 0u,
                     __ATOMIC_RELAXED, __HIP_MEMORY_SCOPE_AGENT);
  __builtin_amdgcn_s_waitcnt(0);
  __syncthreads();
  if (tid==0)
    __hip_atomic_store(myslots + wgd*16, 1u, __ATOMIC_RELAXED, __HIP_MEMORY_SCOPE_AGENT);

  float cstA = 0.f, cstB = 0.f;
  __shared__ __align__(16) unsigned hsh[32*260];   // 32 batches x 256 dwords, +4 pad
  __shared__ float gl[4][16][33];

  // stage ownership: thread covers batch sb, 128B chunk sc
  const int sb = tid >> 3, sc = tid & 7;

  for (int step=0; step<512; ++step){
    const int t = d ? (511-step) : step;
    // xp prefetch (barrier-independent, overlaps the spin)
    short4v x0, x1;
    {
      const size_t gb = (size_t)(d-dir0)*2048 + (size_t)wv*512 + u0 + quad*4;
      x0 = *(const short4v*)(xp + ((size_t)l15*512      + t)*xp_cols + gb);
      x1 = *(const short4v*)(xp + ((size_t)(l15+16)*512 + t)*xp_cols + gb);
    }
    // wait for all 32 WGs of this direction at step `step`
    if (tid < 64){
      const unsigned tgt = (unsigned)(step+1);
      while (true){
        unsigned v = __hip_atomic_load(pollp, __ATOMIC_RELAXED, __HIP_MEMORY_SCOPE_AGENT);
        if (__all((int)(v >= tgt))) break;
        __builtin_amdgcn_s_sleep(1);
      }
    }
    __syncthreads();

    // cooperative stage: 16 independent coherent u64 loads per thread
    {
      const u64* hq = (const u64*)(hstate32 + (size_t)(d*2 + (step&1))*32*256);
      const size_t base = (size_t)sb*128 + sc*16;
      u64 v[16];
#pragma unroll
      for (int k=0;k<16;++k)
        v[k] = __hip_atomic_load(hq + base + k, __ATOMIC_RELAXED, __HIP_MEMORY_SCOPE_AGENT);
      u64* rowp = (u64*)(hsh + (size_t)sb*260 + sc*32);
#pragma unroll
      for (int k=0;k<16;++k) rowp[k] = v[k];
    }
    __syncthreads();

    float4v acc0, acc1;
#pragma unroll
    for (int g=0; g<4; ++g){ acc0[g] = b2f(x0[g]); acc1[g] = b2f(x1[g]); }
    const short* hs = (const short*)hsh;
#pragma unroll
    for (int ks=0; ks<16; ++ks){
      short8 b0 = *(const short8*)(hs + (size_t)l15*520      + ks*32 + quad*8);
      short8 b1 = *(const short8*)(hs + (size_t)(l15+16)*520 + ks*32 + quad*8);
      acc0 = __builtin_amdgcn_mfma_f32_16x16x32_bf16(af[ks], b0, acc0, 0, 0, 0);
      acc1 = __builtin_amdgcn_mfma_f32_16x16x32_bf16(af[ks], b1, acc1, 0, 0, 0);
    }
#pragma unroll
    for (int g=0; g<4; ++g){
      gl[wv][quad*4+g][l15]    = acc0[g];   // gl[gate][unit 0..15][batch 0..31]
      gl[wv][quad*4+g][l15+16] = acc1[g];
    }
    __syncthreads();

    unsigned* hn = hstate32 + (size_t)(d*2 + ((step+1)&1))*32*256;
    float hv[2];
#pragma unroll
    for (int i=0; i<2; ++i){
      const int uu = 2*pp + i;
      const float gi = gl[0][uu][bb], gf = gl[1][uu][bb];
      const float gg = gl[2][uu][bb], go = gl[3][uu][bb];
      float& cref = i ? cstB : cstA;
      const float c = sigm(gf)*cref + sigm(gi)*tanh_(gg);
      cref = c;
      hv[i] = sigm(go) * tanh_(c);
    }
    const unsigned hw = (unsigned)(unsigned short)f2b(hv[0])
                      | ((unsigned)(unsigned short)f2b(hv[1]) << 16);
    __hip_atomic_store(&hn[(size_t)bb*256 + u0/2 + pp], hw,
                       __ATOMIC_RELAXED, __HIP_MEMORY_SCOPE_AGENT);
    *(unsigned*)&hout[((size_t)bb*512 + t)*1024 + d*512 + u0 + 2*pp] = hw;
    __builtin_amdgcn_s_waitcnt(0);   // drain stores to coherence point
    __syncthreads();
    if (tid==0)
      __hip_atomic_store(myslots + wgd*16, (unsigned)(step+2),
                         __ATOMIC_RELAXED, __HIP_MEMORY_SCOPE_AGENT);
  }
}

// ---------------------------------------------------------------------------
// Attention (window_len=1) + classifier. One block per batch element.
// b_u omitted: constant shift cancels in softmax. Output: f32.
// ---------------------------------------------------------------------------
__global__ __launch_bounds__(256) void attn_cls(
    const short* __restrict__ hseq, const short* __restrict__ wu,
    const short* __restrict__ Wc, const short* __restrict__ bc,
    const int* __restrict__ lens, float* __restrict__ out)
{
  const int b = blockIdx.x, tid = threadIdx.x, lane = tid & 63, wv = tid >> 6;
  const int len = lens[b];
  __shared__ float wus[1024];
  __shared__ float sc[512];
  __shared__ float redx[8];
  __shared__ float pooled[1024];
  for (int i=tid; i<1024; i+=256) wus[i] = b2f(wu[i]);
  __syncthreads();
  const short* hb = hseq + (size_t)b*512*1024;
  for (int t=wv; t<512; t+=4){
    const short* hr = hb + (size_t)t*1024;
    float s = 0.f;
#pragma unroll
    for (int j=0;j<16;++j) s += b2f(hr[lane + j*64]) * wus[lane + j*64];
#pragma unroll
    for (int off=32; off>0; off>>=1) s += __shfl_xor(s, off, 64);
    if (lane==0) sc[t] = (t < len) ? s : -3.0e38f;
  }
  __syncthreads();
  float m = -3.0e38f;
  for (int i=tid;i<512;i+=256) m = fmaxf(m, sc[i]);
#pragma unroll
  for (int off=32; off>0; off>>=1) m = fmaxf(m, __shfl_xor(m, off, 64));
  if (lane==0) redx[wv] = m;
  __syncthreads();
  m = fmaxf(fmaxf(redx[0],redx[1]), fmaxf(redx[2],redx[3]));
  float ssum = 0.f;
  for (int i=tid;i<512;i+=256){
    float e = (i<len) ? __expf(sc[i]-m) : 0.f;
    sc[i] = e;
    ssum += e;
  }
#pragma unroll
  for (int off=32; off>0; off>>=1) ssum += __shfl_xor(ssum, off, 64);
  if (lane==0) redx[4+wv] = ssum;
  __syncthreads();
  ssum = redx[4]+redx[5]+redx[6]+redx[7];
  const float inv = 1.f/ssum;
  float4v pa = (float4v)0.f;
  const int k0 = tid*4;
  for (int t=0; t<len; ++t){
    const float a = sc[t];
    short4v hv = *(const short4v*)(hb + (size_t)t*1024 + k0);
    pa[0] += a*b2f(hv[0]); pa[1] += a*b2f(hv[1]);
    pa[2] += a*b2f(hv[2]); pa[3] += a*b2f(hv[3]);
  }
  pooled[k0+0] = pa[0]*inv; pooled[k0+1] = pa[1]*inv;
  pooled[k0+2] = pa[2]*inv; pooled[k0+3] = pa[3]*inv;
  __syncthreads();
  const int j = tid >> 5, l32 = tid & 31;
  float s2 = 0.f;
  for (int kk=l32; kk<1024; kk+=32) s2 += b2f(Wc[j*1024+kk]) * pooled[kk];
#pragma unroll
  for (int off=16; off>0; off>>=1) s2 += __shfl_xor(s2, off, 32);
  if (l32==0) out[b*8+j] = s2 + b2f(bc[j]);
}

// ---------------------------------------------------------------------------
extern "C" void kernel_launch(void* const* d_in, const int* in_sizes, int n_in,
                              void* d_out, int out_size, void* d_ws, size_t ws_size,
                              hipStream_t stream)
{
  (void)in_sizes; (void)n_in; (void)out_size;
  const int*   lens = (const int*)d_in[1];
  float* outp = (float*)d_out;

  const size_t SZ_XP_A = (size_t)16384*4096*2;   // 134,217,728 B
  const size_t SZ_XP_B = (size_t)16384*2048*2;   //  67,108,864 B
  const size_t SZ_H    = (size_t)16384*1024*2;   //  33,554,432 B
  const size_t SZ_HS   = 262144;
  const size_t SZ_CNT  = 16384;
  const size_t SZ_NORM = 37000000;               // bf16 copies of all inputs
  const bool planA = ws_size >= SZ_XP_A + 2*SZ_H + SZ_HS + SZ_CNT + SZ_NORM;
  const bool planB = !planA && ws_size >= SZ_XP_B + 2*SZ_H + SZ_HS + SZ_CNT + SZ_NORM;
  if (!planA && !planB) return;  // clean failure beats a core dump
  const size_t xpsz = planA ? SZ_XP_A : SZ_XP_B;

  char* ws = (char*)d_ws;
  short*    XP  = (short*)ws;
  short*    HB  = (short*)(ws + xpsz);
  short*    HC  = (short*)(ws + xpsz + SZ_H);
  unsigned* HS32= (unsigned*)(ws + xpsz + 2*SZ_H);
  unsigned* CNT = (unsigned*)(ws + xpsz + 2*SZ_H + SZ_HS);
  unsigned* FLAG = CNT + 4000;
  short*    pool = (short*)(ws + xpsz + 2*SZ_H + SZ_HS + SZ_CNT);

  // carve bf16 copies (128-element aligned)
  size_t off = 0;
  auto carve = [&](size_t n){ short* p = pool + off; off += (n + 127) & ~(size_t)127; return p; };
  short* x   = carve(4194304);
  short* W1  = carve(262144);
  short* b1  = carve(1024);
  short* g1  = carve(1024);
  short* be1 = carve(1024);
  short* W2  = carve(1048576);
  short* b2  = carve(1024);
  short* g2  = carve(1024);
  short* be2 = carve(1024);
  short* wih = carve(8388608);
  short* whh = carve(4194304);
  short* bih = carve(8192);
  short* bhh = carve(8192);
  short* wu  = carve(1024);
  short* Wc  = carve(8192);
  short* bc  = carve(8);

  hipMemsetAsync(CNT, 0, SZ_CNT, stream);
  detect_f32<<<1, 256, 0, stream>>>((const unsigned short*)d_in[0], FLAG);

  struct { int idx; short* dst; int n; } cv[16] = {
    {0,x,4194304},{2,W1,262144},{3,b1,1024},{4,g1,1024},{5,be1,1024},
    {6,W2,1048576},{7,b2,1024},{8,g2,1024},{9,be2,1024},
    {10,wih,8388608},{11,whh,4194304},{12,bih,8192},{13,bhh,8192},
    {14,wu,1024},{16,Wc,8192},{17,bc,8}
  };
  for (int i=0;i<16;++i)
    to_bf16<<<(cv[i].n + 255)/256, 256, 0, stream>>>(d_in[cv[i].idx], cv[i].dst, cv[i].n, FLAG);

  dim3 blk(256);
  // extract MLP
  gemm_bt<<<dim3(8,128),  blk, 0, stream>>>(x,  W1, XP, b1, nullptr, 1024, 256);
  ln_lrelu<<<16384, blk, 0, stream>>>(XP, g1, be1, HB, lens, 0);
  gemm_bt<<<dim3(8,128),  blk, 0, stream>>>(HB, W2, XP, b2, nullptr, 1024, 1024);
  ln_lrelu<<<16384, blk, 0, stream>>>(XP, g2, be2, HC, lens, 1);   // + pad mask

  const short* lin[2]  = { HC, HB };   // layer inputs
  short*       lout[2] = { HB, HC };   // layer outputs
  for (int l = 0; l < 2; ++l){
    const short* whh_l = whh + (size_t)l*2*2048*512;
    if (planA){
      gemm_bt<<<dim3(32,128), blk, 0, stream>>>(
          lin[l], wih + (size_t)l*4096*1024, XP,
          bih + l*4096, bhh + l*4096, 4096, 1024);
      lstm_scan<<<64, blk, 0, stream>>>(XP, 4096, 0, whh_l, HS32, lout[l], CNT + l*1024);
    } else {
      for (int d = 0; d < 2; ++d){
        gemm_bt<<<dim3(16,128), blk, 0, stream>>>(
            lin[l], wih + ((size_t)(l*2+d))*2048*1024, XP,
            bih + (l*2+d)*2048, bhh + (l*2+d)*2048, 2048, 1024);
        lstm_scan<<<32, blk, 0, stream>>>(XP, 2048, d, whh_l, HS32, lout[l],
                                          CNT + (l*2+d)*512);
      }
    }
  }
  // attention + classifier
  attn_cls<<<32, blk, 0, stream>>>(HC, wu, Wc, bc, lens, outp);
}